// Round 1
// baseline (28318.515 us; speedup 1.0000x reference)
//
#include <hip/hip_runtime.h>
#include <hip/hip_cooperative_groups.h>

namespace cg = cooperative_groups;

#define SEQL 1024
#define EMB  2048
#define HID  2048
#define G4   8192   // 4*HID
#define NTAG 50

// ---------------------------------------------------------------------------
// Kernel 1: x_gates[t][n] = sum_k emb[seq[t]][k] * W_ih[n][k] + b_ih[n] + b_hh[n]
// f32 tiled GEMM, 128x128 tile, 256 threads, 8x8 micro-tile per thread.
// ---------------------------------------------------------------------------
__global__ __launch_bounds__(256) void gemm_xgates(
    const int* __restrict__ seq, const float* __restrict__ emb,
    const float* __restrict__ Wih, const float* __restrict__ bih,
    const float* __restrict__ bhh, float* __restrict__ xg)
{
    constexpr int BM = 128, BN = 128, BK = 32;
    __shared__ float As[BK][BM + 4];   // stored transposed: As[k][m]
    __shared__ float Bs[BK][BN + 4];
    __shared__ int   srow[BM];

    const int tid = threadIdx.x;
    const int bn = blockIdx.x, bm = blockIdx.y;

    if (tid < BM) srow[tid] = seq[bm * BM + tid];
    __syncthreads();

    const int tx = tid & 15, ty = tid >> 4;
    const int c4 = tid & 7;          // float4 column within BK
    const int r0 = tid >> 3;         // row 0..31 (4 batches of 32)

    float acc[8][8] = {};

    for (int k0 = 0; k0 < EMB; k0 += BK) {
        #pragma unroll
        for (int i = 0; i < 4; ++i) {
            const int r = r0 + 32 * i;
            float4 av = *(const float4*)(emb + (size_t)srow[r] * EMB + k0 + 4 * c4);
            As[4*c4+0][r] = av.x; As[4*c4+1][r] = av.y;
            As[4*c4+2][r] = av.z; As[4*c4+3][r] = av.w;
            float4 bv = *(const float4*)(Wih + (size_t)(bn * BN + r) * EMB + k0 + 4 * c4);
            Bs[4*c4+0][r] = bv.x; Bs[4*c4+1][r] = bv.y;
            Bs[4*c4+2][r] = bv.z; Bs[4*c4+3][r] = bv.w;
        }
        __syncthreads();
        #pragma unroll
        for (int kk = 0; kk < BK; ++kk) {
            float a[8], b[8];
            *(float4*)&a[0] = *(const float4*)&As[kk][8*ty];
            *(float4*)&a[4] = *(const float4*)&As[kk][8*ty+4];
            *(float4*)&b[0] = *(const float4*)&Bs[kk][8*tx];
            *(float4*)&b[4] = *(const float4*)&Bs[kk][8*tx+4];
            #pragma unroll
            for (int i = 0; i < 8; ++i)
                #pragma unroll
                for (int j = 0; j < 8; ++j)
                    acc[i][j] += a[i] * b[j];
        }
        __syncthreads();
    }

    const int gm = bm * BM + 8 * ty;
    const int gn = bn * BN + 8 * tx;
    float bb[8];
    #pragma unroll
    for (int j = 0; j < 8; ++j) bb[j] = bih[gn + j] + bhh[gn + j];
    #pragma unroll
    for (int i = 0; i < 8; ++i) {
        float4 o0, o1;
        o0.x = acc[i][0] + bb[0]; o0.y = acc[i][1] + bb[1];
        o0.z = acc[i][2] + bb[2]; o0.w = acc[i][3] + bb[3];
        o1.x = acc[i][4] + bb[4]; o1.y = acc[i][5] + bb[5];
        o1.z = acc[i][6] + bb[6]; o1.w = acc[i][7] + bb[7];
        *(float4*)(xg + (size_t)(gm + i) * G4 + gn)     = o0;
        *(float4*)(xg + (size_t)(gm + i) * G4 + gn + 4) = o1;
    }
}

// ---------------------------------------------------------------------------
// Kernel 2: persistent cooperative LSTM recurrence.
// 256 wgs x 512 threads (1 wg/CU). W_hh held entirely in registers:
// wave w of wg g owns hidden unit j = 8g+w; lane l holds
// wt[q][x] = W_hh[q*HID + j][32*l + x]  (4 gate rows x 32 k-elems, f32).
// Per step: h staged in LDS (XOR-swizzled float4 chunks), 128 FMA/lane,
// 64-lane butterfly reduce -> gates -> c (register) -> h[j] -> grid.sync().
// ---------------------------------------------------------------------------
__device__ __forceinline__ float sigm_(float x) { return 1.0f / (1.0f + __expf(-x)); }
__device__ __forceinline__ float tanh_(float x) {
    float e = __expf(2.0f * x);
    return (e - 1.0f) / (e + 1.0f);
}

__global__ __launch_bounds__(512, 2) void lstm_recur(
    const float* __restrict__ Whh, const float* __restrict__ xg,
    const float* __restrict__ Wtag, const float* __restrict__ btag,
    float* __restrict__ hbuf, float* __restrict__ tags, float* __restrict__ out)
{
    cg::grid_group grid = cg::this_grid();
    __shared__ float sh_h[HID];
    __shared__ float sh_red[8];

    const int tid = threadIdx.x;
    const int wv  = tid >> 6;              // wave 0..7
    const int l   = tid & 63;              // lane
    const int j   = 8 * blockIdx.x + wv;   // hidden unit owned by this wave

    // Load W_hh slice into registers (f32, full precision).
    float wt[4][32];
    #pragma unroll
    for (int q = 0; q < 4; ++q) {
        const float* wr = Whh + (size_t)(q * HID + j) * HID + 32 * l;
        #pragma unroll
        for (int x = 0; x < 8; ++x)
            *(float4*)&wt[q][4*x] = *(const float4*)(wr + 4*x);
    }

    float c = 0.0f;
    float4* sh4 = (float4*)sh_h;

    for (int t = 0; t < SEQL; ++t) {
        if (t > 0) {
            // stage h_{t-1} into LDS, XOR-swizzled 16B chunks (bank spread)
            const float4* hp = (const float4*)(hbuf + ((t + 1) & 1) * HID);
            sh4[tid ^ ((tid >> 3) & 7)] = hp[tid];
        }
        __syncthreads();

        // xg loads are independent of LDS — issue early
        const size_t xb = (size_t)t * G4 + j;
        const float xg0 = xg[xb];
        const float xg1 = xg[xb + HID];
        const float xg2 = xg[xb + 2 * HID];
        const float xg3 = xg[xb + 3 * HID];

        float s0 = 0.f, s1 = 0.f, s2 = 0.f, s3 = 0.f;
        if (t > 0) {
            #pragma unroll
            for (int i = 0; i < 8; ++i) {
                // original chunk 8l+i was stored at (8l+i) ^ (l&7)
                float4 h4 = sh4[8 * l + (i ^ (l & 7))];
                s0 += wt[0][4*i]*h4.x + wt[0][4*i+1]*h4.y + wt[0][4*i+2]*h4.z + wt[0][4*i+3]*h4.w;
                s1 += wt[1][4*i]*h4.x + wt[1][4*i+1]*h4.y + wt[1][4*i+2]*h4.z + wt[1][4*i+3]*h4.w;
                s2 += wt[2][4*i]*h4.x + wt[2][4*i+1]*h4.y + wt[2][4*i+2]*h4.z + wt[2][4*i+3]*h4.w;
                s3 += wt[3][4*i]*h4.x + wt[3][4*i+1]*h4.y + wt[3][4*i+2]*h4.z + wt[3][4*i+3]*h4.w;
            }
        }
        #pragma unroll
        for (int m = 1; m < 64; m <<= 1) {
            s0 += __shfl_xor(s0, m);
            s1 += __shfl_xor(s1, m);
            s2 += __shfl_xor(s2, m);
            s3 += __shfl_xor(s3, m);
        }
        const float gi = sigm_(s0 + xg0);
        const float gf = sigm_(s1 + xg1);
        const float gg = tanh_(s2 + xg2);
        const float go = sigm_(s3 + xg3);
        c = gf * c + gi * gg;
        const float h = go * tanh_(c);
        if (l == 0) hbuf[(t & 1) * HID + j] = h;
        grid.sync();
    }

    // ---- tag projection: wgs 0..49 each compute one tag row ----
    const float* hfin = hbuf + HID;   // t=1023 wrote buffer 1
    if (blockIdx.x < NTAG) {
        float4 wv4 = *(const float4*)(Wtag + (size_t)blockIdx.x * HID + 4 * tid);
        float4 hv4 = *(const float4*)(hfin + 4 * tid);
        float part = wv4.x*hv4.x + wv4.y*hv4.y + wv4.z*hv4.z + wv4.w*hv4.w;
        #pragma unroll
        for (int m = 1; m < 64; m <<= 1) part += __shfl_xor(part, m);
        if (l == 0) sh_red[wv] = part;
    }
    __syncthreads();
    if (blockIdx.x < NTAG && tid == 0) {
        float s = 0.f;
        #pragma unroll
        for (int i = 0; i < 8; ++i) s += sh_red[i];
        tags[blockIdx.x] = s + btag[blockIdx.x];
    }
    grid.sync();

    // ---- log_softmax over 50 tags (wg 0, wave 0) ----
    if (blockIdx.x == 0 && tid < 64) {
        float v = (tid < NTAG) ? tags[tid] : -3.0e38f;
        float mx = v;
        #pragma unroll
        for (int m = 1; m < 64; m <<= 1) mx = fmaxf(mx, __shfl_xor(mx, m));
        float e = (tid < NTAG) ? __expf(v - mx) : 0.f;
        float se = e;
        #pragma unroll
        for (int m = 1; m < 64; m <<= 1) se += __shfl_xor(se, m);
        if (tid < NTAG) out[tid] = v - mx - __logf(se);
    }
}

// ---------------------------------------------------------------------------
extern "C" void kernel_launch(void* const* d_in, const int* in_sizes, int n_in,
                              void* d_out, int out_size, void* d_ws, size_t ws_size,
                              hipStream_t stream)
{
    const int*   seq  = (const int*)d_in[0];
    const float* emb  = (const float*)d_in[1];
    const float* Wih  = (const float*)d_in[2];
    const float* Whh  = (const float*)d_in[3];
    const float* bih  = (const float*)d_in[4];
    const float* bhh  = (const float*)d_in[5];
    const float* Wtag = (const float*)d_in[6];
    const float* btag = (const float*)d_in[7];
    float* out = (float*)d_out;

    float* xg   = (float*)d_ws;                    // 1024*8192 f32 = 32 MiB
    float* hbuf = xg + (size_t)SEQL * G4;          // 2*2048 f32 (double buffer)
    float* tags = hbuf + 2 * HID;                  // 50 f32

    dim3 g1(G4 / 128, SEQL / 128);                 // (64, 8)
    gemm_xgates<<<g1, 256, 0, stream>>>(seq, emb, Wih, bih, bhh, xg);

    void* args[] = {(void*)&Whh, (void*)&xg, (void*)&Wtag, (void*)&btag,
                    (void*)&hbuf, (void*)&tags, (void*)&out};
    hipLaunchCooperativeKernel((void*)lstm_recur, dim3(256), dim3(512),
                               args, 0, stream);
}